// Round 6
// baseline (312.799 us; speedup 1.0000x reference)
//
#include <hip/hip_runtime.h>

#define T_STEPS 512
#define G_CELLS 4096
#define HALF_G  (G_CELLS / 2)
#define L_UHN   15
#define GRP     4
#define NZF     1e-5f
#define LOG2E   1.44269504088896340736f
#define LOG2_10 3.32192809488736234787f

// raw gfx950 transcendental units: v_exp_f32 computes 2^x, v_log_f32 computes log2(x)
__device__ __forceinline__ float fexp2(float x) { return __builtin_amdgcn_exp2f(x); }
__device__ __forceinline__ float flog2(float x) { return __builtin_amdgcn_logf(x); }

__device__ __forceinline__ float fpow(float a, float b) {   // a > 0
    return fexp2(b * flog2(a));
}
__device__ __forceinline__ float fexp(float x) {            // e^x
    return fexp2(x * LOG2E);
}
__device__ __forceinline__ float fsigmoid(float v) {
    return 1.0f / (1.0f + fexp(-v));
}
__device__ __forceinline__ float fdescale(float s, float lo, float hi) {
    return lo + s * (hi - lo);
}

struct Cell {
    // ---- per-cell constants ----
    float ddfsum, ddfK, ddf_min, Tbm, Kf, Tbf, SWI, exp_fe, fcsum, fcmin, Ccum;
    float inv_vmax, hbv_beta, vic_beta, hmets_alpha;
    float w1, w2, w3, w4, w5, w6, w8, w9;
    float w7qk, c_b1, c_b2, baseflow_n, quickflow_n, qf_top_coef, mmax, ET_eff, cv2p;
    float uh1[L_UHN], uh2[L_UHN];
    // ---- state ----
    float sp1, lw1, cm1, sp2, lw2, cm2, sp3, cm3, vad, phr;
    float fut[L_UHN];
};

__device__ __forceinline__ void unpack_cell(const float* __restrict__ pp, Cell& c) {
    float raw[39];
    #pragma unroll
    for (int i = 0; i < 39; ++i) raw[i] = pp[i];

    const float ddf_min     = fdescale(fsigmoid(raw[0]),  0.0f, 20.0f);
    const float ddf_plus    = fdescale(fsigmoid(raw[1]),  0.0f, 20.0f);
    const float Kcum        = fdescale(fsigmoid(raw[2]),  0.01f, 0.2f);
    c.Kf                    = fdescale(fsigmoid(raw[3]),  0.0f, 5.0f);
    c.exp_fe                = fdescale(fsigmoid(raw[4]),  0.0f, 1.0f);
    c.Tbf                   = fdescale(fsigmoid(raw[5]), -5.0f, 2.0f);
    c.Ccum                  = fdescale(fsigmoid(raw[6]),  0.005f, 0.05f);
    c.SWI                   = fdescale(fsigmoid(raw[7]),  0.0f, 0.4f);
    c.Tbm                   = fdescale(fsigmoid(raw[8]), -2.0f, 3.0f);
    c.fcmin                 = fdescale(fsigmoid(raw[9]),  0.0f, 0.1f);
    const float fcmin_plus  = fdescale(fsigmoid(raw[10]), 0.01f, 0.25f);
    const float vmax        = fdescale(fsigmoid(raw[11]), 0.001f, 500.0f);
    c.hmets_alpha           = fdescale(fsigmoid(raw[12]), 0.0f, 1.0f);
    c.vic_beta              = fdescale(fsigmoid(raw[13]), 0.1f, 3.0f);
    c.hbv_beta              = fdescale(fsigmoid(raw[14]), 0.5f, 3.0f);
    const float quickflow_k = fdescale(fsigmoid(raw[15]), -5.0f, -2.0f);
    c.quickflow_n           = fdescale(fsigmoid(raw[16]), 0.5f, 2.0f);
    c.mmax                  = fdescale(fsigmoid(raw[17]), 0.0f, 100.0f);
    const float lamb        = fdescale(fsigmoid(raw[18]), 5.0f, 10.0f);
    const float baseflow_k  = fdescale(fsigmoid(raw[19]), -5.0f, -1.0f);
    c.baseflow_n            = fdescale(fsigmoid(raw[20]), 0.5f, 2.0f);
    c.ET_eff                = fdescale(fsigmoid(raw[21]), 0.0f, 3.0f);
    c.cv2p                  = fdescale(fsigmoid(raw[22]), 1e-5f, 0.02f);

    float w7, w10, w11;
    {
        float m = fmaxf(fmaxf(raw[24], raw[25]), raw[26]);
        float e0 = fexp(raw[24] - m), e1 = fexp(raw[25] - m), e2 = fexp(raw[26] - m);
        float inv = 1.0f / (e0 + e1 + e2);
        c.w1 = e0 * inv; c.w2 = e1 * inv; c.w3 = e2 * inv;
    }
    {
        float m = fmaxf(fmaxf(raw[27], raw[28]), raw[29]);
        float e0 = fexp(raw[27] - m), e1 = fexp(raw[28] - m), e2 = fexp(raw[29] - m);
        float inv = 1.0f / (e0 + e1 + e2);
        c.w4 = e0 * inv; c.w5 = e1 * inv; c.w6 = e2 * inv;
    }
    {
        float m = fmaxf(fmaxf(raw[30], raw[31]), raw[32]);
        float e0 = fexp(raw[30] - m), e1 = fexp(raw[31] - m), e2 = fexp(raw[32] - m);
        float inv = 1.0f / (e0 + e1 + e2);
        w7 = e0 * inv; c.w8 = e1 * inv; c.w9 = e2 * inv;
    }
    {
        float m = fmaxf(raw[33], raw[34]);
        float e0 = fexp(raw[33] - m), e1 = fexp(raw[34] - m);
        float inv = 1.0f / (e0 + e1);
        w10 = e0 * inv; w11 = e1 * inv;
    }

    const float a1 = fdescale(fsigmoid(raw[35]), 0.3f, 20.0f);
    const float b1 = fdescale(fsigmoid(raw[36]), 0.01f, 5.0f);
    const float a2 = fdescale(fsigmoid(raw[37]), 0.5f, 13.0f);
    const float b2 = fdescale(fsigmoid(raw[38]), 0.15f, 1.5f);

    const float LOG2T[L_UHN] = {
        -1.0f, 0.58496250072116f, 1.32192809488736f, 1.80735492205760f,
        2.16992500144231f, 2.45943161863730f, 2.70043971814109f,
        2.90689059560852f, 3.08746284125034f, 3.24792751344359f,
        3.39231742277876f, 3.52356195605701f, 3.64385618977472f,
        3.75488750216347f, 3.85798099512757f };

    {
        float rb1 = LOG2E / b1, rb2 = LOG2E / b2;
        float s1 = 0.0f, s2 = 0.0f;
        #pragma unroll
        for (int k = 0; k < L_UHN; ++k) {
            float tk = (float)k + 0.5f;
            float v1 = fexp2((a1 - 1.0f) * LOG2T[k] - tk * rb1);
            float v2 = fexp2((a2 - 1.0f) * LOG2T[k] - tk * rb2);
            c.uh1[k] = v1; c.uh2[k] = v2; s1 += v1; s2 += v2;
        }
        float i1 = 1.0f / s1, i2 = 1.0f / s2;
        #pragma unroll
        for (int k = 0; k < L_UHN; ++k) { c.uh1[k] *= i1; c.uh2[k] *= i2; }
    }

    c.ddf_min      = ddf_min;
    c.ddfsum       = ddf_min + ddf_plus;
    c.ddfK         = ddf_min * Kcum;
    c.inv_vmax     = 1.0f / vmax;
    const float qk10 = fexp2(quickflow_k * LOG2_10);
    const float bk10 = fexp2(baseflow_k * LOG2_10);
    c.qf_top_coef  = c.mmax * (vmax / c.quickflow_n) * fexp2(-c.quickflow_n * flog2(lamb));
    c.fcsum        = c.fcmin + fcmin_plus;
    c.c_b1         = w10 * bk10;
    c.c_b2         = w11 * bk10;
    c.w7qk         = w7 * qk10;

    c.sp1 = 0.f; c.lw1 = 0.f; c.cm1 = 0.f;
    c.sp2 = 0.f; c.lw2 = 0.f; c.cm2 = 0.f;
    c.sp3 = 0.f; c.cm3 = 0.f;
    c.vad = 0.f; c.phr = 0.f;
    #pragma unroll
    for (int k = 0; k < L_UHN; ++k) c.fut[k] = 0.0f;
}

__device__ __forceinline__ float step_cell(Cell& c, float prcp, float tm, float pet) {
    const float rain = (tm > 0.0f) ? prcp : 0.0f;
    const float snow = prcp - rain;
    const float frz_pot = fmaxf(c.Tbf - tm, NZF);

    // --- snobal_hbv ---
    float o1;
    {
        float ddf  = fminf(c.ddfsum, fmaf(c.ddfK, c.cm1, c.ddf_min));
        float pm   = fmaxf(ddf * (tm - c.Tbm), 0.0f);
        float rfz  = fminf(c.Kf * frz_pot, c.lw1);
        c.sp1 = c.sp1 + snow + rfz;
        float melt = fminf(pm, c.sp1 + snow + rfz);   // reference quirk: sp already updated
        c.cm1 = (c.sp1 > NZF) ? (c.cm1 + melt) : 0.0f;
        c.sp1 = fmaxf(c.sp1 - melt, NZF);
        float wret = c.SWI * c.sp1;
        float wtmp = c.lw1 + melt + rain;
        o1 = fmaxf(wtmp - wret, 0.0f);
        c.lw1 = fminf(wtmp, wret);                    // == (ovf>0 ? wret : wtmp)
    }

    // --- snobal_hmets ---
    float o2;
    {
        float ddf  = fminf(c.ddfsum, fmaf(c.ddfK, c.cm2, c.ddf_min));
        float pm   = fmaxf(ddf * (tm - c.Tbm), 0.0f);
        float pfz  = c.Kf * fpow(frz_pot, c.exp_fe);
        float rfz  = fminf(pfz, c.lw2);
        c.lw2 = c.lw2 - rfz;
        c.sp2 = c.sp2 + rfz;
        float melt = fminf(pm, c.sp2 + snow);
        c.sp2 = c.sp2 + snow - melt;
        c.cm2 = (c.sp2 > NZF) ? (c.cm2 + melt) : 0.0f;
        float wrf  = fmaxf(c.fcsum * (1.0f - c.Ccum * c.cm2), c.fcmin);
        float wret = wrf * c.sp2;
        float wtmp = c.lw2 + melt + rain;
        o2 = fmaxf(wtmp - wret, 0.0f);
        c.lw2 = fminf(wtmp, wret);
        c.cm2 = (c.sp2 > NZF) ? (c.cm2 + melt) : 0.0f;  // reference quirk: cm updated twice
    }

    // --- snobal_simple ---
    float o3;
    {
        float ddf  = fminf(c.ddfsum, fmaf(c.ddfK, c.cm3, c.ddf_min));
        float pm   = fmaxf(ddf * (tm - c.Tbm), 0.0f);
        float melt = fminf(pm, c.sp3);
        c.sp3 = c.sp3 + snow - melt;
        o3 = melt + rain;
        c.cm3 = (c.sp3 > NZF) ? (c.cm3 + melt) : 0.0f;
    }

    // --- vadose / phreatic chain ---
    float rr = c.w1 * o1 + c.w2 * o2 + c.w3 * o3;
    float vv = c.vad * c.inv_vmax;
    float sprop = fminf(fmaxf(vv, NZF), 1.0f - NZF);
    float l1 = flog2(1.0f - sprop);
    float phbv = fexp2(c.hbv_beta * l1);
    float pvic = fexp2(c.vic_beta * l1);
    float inf = c.w4 * rr * phbv + c.w5 * rr * (1.0f - c.hmets_alpha * vv) + c.w6 * rr * (1.0f - pvic);
    inf = fminf(fmaxf(inf, 0.0f), rr);
    float surface = rr - inf;
    c.vad += inf;
    vv = c.vad * c.inv_vmax;
    sprop = fminf(fmaxf(vv, NZF), 1.0f - NZF);
    float et = fminf(pet * c.ET_eff * sprop, c.vad);
    c.vad -= et;
    float spq    = fexp2(c.quickflow_n * flog2(sprop));
    float qf_top = fminf(c.qf_top_coef * spq, c.vad);
    float qf_vic = fminf(c.mmax * spq, c.vad);
    float qf = fminf(c.w7qk * c.vad + c.w8 * qf_top + c.w9 * qf_vic, c.vad);
    c.vad -= qf;
    float perc = c.cv2p * c.vad;
    c.vad -= perc;
    c.phr += perc;
    float pb = fexp2(c.baseflow_n * flog2(fmaxf(c.phr, NZF)));
    float bf = fminf(c.c_b1 * c.phr + c.c_b2 * pb, c.phr);
    c.phr -= bf;

    const float qt = surface + qf;
    const float bt = bf;

    // --- fused routing: rolling 15-wide future window ---
    #pragma unroll
    for (int k = 0; k < L_UHN; ++k)
        c.fut[k] = fmaf(c.uh1[k], qt, fmaf(c.uh2[k], bt, c.fut[k]));
    float result = c.fut[0];
    #pragma unroll
    for (int k = 0; k < L_UHN - 1; ++k) c.fut[k] = c.fut[k + 1];
    c.fut[L_UHN - 1] = 0.0f;
    return result;
}

__global__ __launch_bounds__(256, 1) void blend_scan_kernel(
    const float* __restrict__ x,       // (T, G, 3)
    const float* __restrict__ params,  // (T, G, 39)
    float* __restrict__ out)           // (T, G)
{
    const int ga = blockIdx.x * blockDim.x + threadIdx.x;   // [0, 2048)
    const int gb = ga + HALF_G;                             // [2048, 4096)

    Cell ca, cb;
    unpack_cell(params + ((size_t)(T_STEPS - 1) * G_CELLS + (size_t)ga) * 39, ca);
    unpack_cell(params + ((size_t)(T_STEPS - 1) * G_CELLS + (size_t)gb) * 39, cb);

    // ---- double-buffered forcing prefetch: GRP steps per group, 2 cells ----
    float cxa[GRP][3], nxa[GRP][3], cxb[GRP][3], nxb[GRP][3];
    #pragma unroll
    for (int j = 0; j < GRP; ++j) {
        size_t aa = ((size_t)j * G_CELLS + (size_t)ga) * 3;
        size_t ab = ((size_t)j * G_CELLS + (size_t)gb) * 3;
        cxa[j][0] = x[aa]; cxa[j][1] = x[aa + 1]; cxa[j][2] = x[aa + 2];
        cxb[j][0] = x[ab]; cxb[j][1] = x[ab + 1]; cxb[j][2] = x[ab + 2];
    }

    for (int tb = 0; tb < T_STEPS / GRP; ++tb) {
        const int base_next = (tb + 1) * GRP;
        #pragma unroll
        for (int j = 0; j < GRP; ++j) {
            int tt = base_next + j;
            if (tt >= T_STEPS) tt = T_STEPS - 1;   // harmless clamp for final group
            size_t aa = ((size_t)tt * G_CELLS + (size_t)ga) * 3;
            size_t ab = ((size_t)tt * G_CELLS + (size_t)gb) * 3;
            nxa[j][0] = x[aa]; nxa[j][1] = x[aa + 1]; nxa[j][2] = x[aa + 2];
            nxb[j][0] = x[ab]; nxb[j][1] = x[ab + 1]; nxb[j][2] = x[ab + 2];
        }

        #pragma unroll
        for (int j = 0; j < GRP; ++j) {
            const int t = tb * GRP + j;
            float ra = step_cell(ca, cxa[j][0], cxa[j][1], cxa[j][2]);
            float rb = step_cell(cb, cxb[j][0], cxb[j][1], cxb[j][2]);
            out[(size_t)t * G_CELLS + ga] = ra;
            out[(size_t)t * G_CELLS + gb] = rb;
        }

        #pragma unroll
        for (int j = 0; j < GRP; ++j) {
            cxa[j][0] = nxa[j][0]; cxa[j][1] = nxa[j][1]; cxa[j][2] = nxa[j][2];
            cxb[j][0] = nxb[j][0]; cxb[j][1] = nxb[j][1]; cxb[j][2] = nxb[j][2];
        }
    }
}

extern "C" void kernel_launch(void* const* d_in, const int* in_sizes, int n_in,
                              void* d_out, int out_size, void* d_ws, size_t ws_size,
                              hipStream_t stream) {
    const float* x      = (const float*)d_in[0];
    const float* params = (const float*)d_in[1];
    float* out          = (float*)d_out;
    blend_scan_kernel<<<dim3(HALF_G / 256), dim3(256), 0, stream>>>(x, params, out);
}